// Round 5
// baseline (213.085 us; speedup 1.0000x reference)
//
#include <hip/hip_runtime.h>

#define B_ 2
#define N_ 2048
#define H_ 1024
#define NH_ 16
#define D_ 64

typedef _Float16 f16;
typedef _Float16 f16x4 __attribute__((ext_vector_type(4)));
typedef _Float16 f16x8 __attribute__((ext_vector_type(8)));
typedef float f32x4 __attribute__((ext_vector_type(4)));

#define MFMA16(a, b, c) __builtin_amdgcn_mfma_f32_16x16x32_f16((a), (b), (c), 0, 0, 0)
#define MFMA16K(a, b, c) __builtin_amdgcn_mfma_f32_16x16x16f16((a), (b), (c), 0, 0, 0)

// async global->LDS, 16B per lane; lds dest = base + lane*16 (wave-uniform base)
__device__ __forceinline__ void cp16(void* lds, const void* g) {
  __builtin_amdgcn_global_load_lds(
      (const __attribute__((address_space(1))) void*)g,
      (__attribute__((address_space(3))) void*)lds, 16, 0, 0);
}

// ---------------------------------------------------------------------------
// fp32 -> f16 convert (x, x2), 8 elems/thread
// ---------------------------------------------------------------------------
__global__ __launch_bounds__(256) void convf16(
    const float* __restrict__ a, const float* __restrict__ b,
    f16* __restrict__ ao, f16* __restrict__ bo) {
  const size_t i = ((size_t)blockIdx.x * 256 + threadIdx.x) * 8;
  const float* __restrict__ src = (blockIdx.y == 0) ? a : b;
  f16* __restrict__ dst = (blockIdx.y == 0) ? ao : bo;
  float4 v0 = ((const float4*)(src + i))[0];
  float4 v1 = ((const float4*)(src + i))[1];
  f16x8 o;
  o[0] = (f16)v0.x; o[1] = (f16)v0.y; o[2] = (f16)v0.z; o[3] = (f16)v0.w;
  o[4] = (f16)v1.x; o[5] = (f16)v1.y; o[6] = (f16)v1.z; o[7] = (f16)v1.w;
  *(f16x8*)(dst + i) = o;
}

// ---------------------------------------------------------------------------
// Transpose+convert: W f32 [rows][ncols] -> Wt f16 [ncols][rows]
// ---------------------------------------------------------------------------
__global__ __launch_bounds__(256) void transw(
    const float* __restrict__ W, f16* __restrict__ Wt, int rows, int ncols) {
  const int cb = blockIdx.x * 64, kb = blockIdx.y * 64;
  const int t = threadIdx.x;
  __shared__ f16 T[64][72];
  {
    const int k = t >> 2, c0 = (t & 3) * 16;
    const float* wp = W + (size_t)(kb + k) * ncols + cb + c0;
    float4 w0 = ((const float4*)wp)[0];
    float4 w1 = ((const float4*)wp)[1];
    float4 w2 = ((const float4*)wp)[2];
    float4 w3 = ((const float4*)wp)[3];
    T[c0 + 0][k] = (f16)w0.x;  T[c0 + 1][k] = (f16)w0.y;
    T[c0 + 2][k] = (f16)w0.z;  T[c0 + 3][k] = (f16)w0.w;
    T[c0 + 4][k] = (f16)w1.x;  T[c0 + 5][k] = (f16)w1.y;
    T[c0 + 6][k] = (f16)w1.z;  T[c0 + 7][k] = (f16)w1.w;
    T[c0 + 8][k] = (f16)w2.x;  T[c0 + 9][k] = (f16)w2.y;
    T[c0 + 10][k] = (f16)w2.z; T[c0 + 11][k] = (f16)w2.w;
    T[c0 + 12][k] = (f16)w3.x; T[c0 + 13][k] = (f16)w3.y;
    T[c0 + 14][k] = (f16)w3.z; T[c0 + 15][k] = (f16)w3.w;
  }
  __syncthreads();
  {
    const int c = t >> 2, k0 = (t & 3) * 16;
    f16* op = Wt + (size_t)(cb + c) * rows + kb + k0;
    *(f16x8*)(op + 0) = *(const f16x8*)(&T[c][k0]);
    *(f16x8*)(op + 8) = *(const f16x8*)(&T[c][k0 + 8]);
  }
}

// ---------------------------------------------------------------------------
// Transpose V: f16 [bh][N][D] -> Vt f16 [bh][D][N]
// ---------------------------------------------------------------------------
__global__ __launch_bounds__(256) void transv(
    const f16* __restrict__ V, f16* __restrict__ Vt) {
  const int nb = blockIdx.x * 64, bh = blockIdx.y;
  const int t = threadIdx.x;
  __shared__ f16 T[64][72];
  {
    const int n = t >> 2, d0 = (t & 3) * 16;
    const f16* vp = V + ((size_t)bh * N_ + nb + n) * D_ + d0;
    f16x8 v0 = *(const f16x8*)(vp);
    f16x8 v1 = *(const f16x8*)(vp + 8);
#pragma unroll
    for (int i = 0; i < 8; ++i) T[d0 + i][n] = v0[i];
#pragma unroll
    for (int i = 0; i < 8; ++i) T[d0 + 8 + i][n] = v1[i];
  }
  __syncthreads();
  {
    const int d = t >> 2, n0 = (t & 3) * 16;
    f16* op = Vt + ((size_t)bh * D_ + d) * N_ + nb + n0;
    *(f16x8*)(op + 0) = *(const f16x8*)(&T[d][n0]);
    *(f16x8*)(op + 8) = *(const f16x8*)(&T[d][n0 + 8]);
  }
}

// ---------------------------------------------------------------------------
// QKV GEMM, m97-style: C[4096,3072] = A_f16 @ WqkvT_f16^T.
// 128x128 tile, BK=32, global_load_lds staging with XOR granule swizzle.
// Q scaled by 0.125*log2(e) (exp2-softmax downstream). bid: row-fastest.
// ---------------------------------------------------------------------------
__global__ __launch_bounds__(256) void qkv_mfma(
    const f16* __restrict__ Xc, const f16* __restrict__ X2c,
    const f16* __restrict__ Wt, f16* __restrict__ Qo,
    f16* __restrict__ Ko, f16* __restrict__ Vo) {
  const int bid = blockIdx.x;
  const int rb = (bid & 31) * 128;
  const int cb = (bid >> 5) * 128;
  const int t = threadIdx.x;
  const int lane = t & 63, wid = t >> 6;
  const int quad = lane >> 4, n16 = lane & 15;
  const int wm = wid >> 1, wn = wid & 1;

  const f16* __restrict__ A = (cb < H_) ? Xc : X2c;
  const int seg = cb >> 10;
  const float qscale = (seg == 0) ? 0.125f * 1.44269504f : 1.0f;
  f16* __restrict__ outp = (seg == 0) ? Qo : (seg == 1 ? Ko : Vo);

  __shared__ f16 As[128 * 32];  // [row][k], 64B rows, swizzled granules
  __shared__ f16 Bs[128 * 32];  // [col][k]

  f32x4 acc[4][4];
#pragma unroll
  for (int i = 0; i < 4; ++i)
#pragma unroll
    for (int j = 0; j < 4; ++j) acc[i][j] = (f32x4){0.f, 0.f, 0.f, 0.f};

  int srow0 = wid * 16 + (lane >> 2);
  int srow1 = 64 + srow0;
  int gl0 = ((lane & 3) ^ ((srow0 >> 1) & 3)) * 8;
  int gl1 = ((lane & 3) ^ ((srow1 >> 1) & 3)) * 8;
  const f16* gA0 = A + (size_t)(rb + srow0) * H_ + gl0;
  const f16* gA1 = A + (size_t)(rb + srow1) * H_ + gl1;
  const f16* gB0 = Wt + (size_t)(cb + srow0) * H_ + gl0;
  const f16* gB1 = Wt + (size_t)(cb + srow1) * H_ + gl1;
  f16* lA0 = &As[wid * 512];
  f16* lA1 = &As[2048 + wid * 512];
  f16* lB0 = &Bs[wid * 512];
  f16* lB1 = &Bs[2048 + wid * 512];

  const int fsw = (quad ^ ((n16 >> 1) & 3)) * 8;
  int aoff[4], boff[4];
#pragma unroll
  for (int i = 0; i < 4; ++i) {
    aoff[i] = (wm * 64 + i * 16 + n16) * 32 + fsw;
    boff[i] = (wn * 64 + i * 16 + n16) * 32 + fsw;
  }

  for (int kt = 0; kt < H_; kt += 32) {
    __syncthreads();
    cp16(lA0, gA0); cp16(lA1, gA1);
    cp16(lB0, gB0); cp16(lB1, gB1);
    gA0 += 32; gA1 += 32; gB0 += 32; gB1 += 32;
    __syncthreads();

    f16x8 af[4], bf[4];
#pragma unroll
    for (int mt = 0; mt < 4; ++mt) af[mt] = *(const f16x8*)(&As[aoff[mt]]);
#pragma unroll
    for (int nt = 0; nt < 4; ++nt) bf[nt] = *(const f16x8*)(&Bs[boff[nt]]);
#pragma unroll
    for (int mt = 0; mt < 4; ++mt)
#pragma unroll
      for (int nt = 0; nt < 4; ++nt)
        acc[mt][nt] = MFMA16(af[mt], bf[nt], acc[mt][nt]);
  }

#pragma unroll
  for (int mt = 0; mt < 4; ++mt)
#pragma unroll
    for (int nt = 0; nt < 4; ++nt)
#pragma unroll
      for (int r = 0; r < 4; ++r) {
        int grow = rb + wm * 64 + mt * 16 + quad * 4 + r;
        int gcol = cb + wn * 64 + nt * 16 + n16;
        int bb = grow >> 11, nn = grow & 2047;
        int hh = (gcol >> 6) & 15, dd = gcol & 63;
        outp[(((size_t)(bb * NH_ + hh)) * N_ + nn) * D_ + dd] =
            (f16)(acc[mt][nt][r] * qscale);
      }
}

// ---------------------------------------------------------------------------
// Flash attention v3: P never touches LDS.
// S^T = K@Q^T via 16x16x32 MFMA; its C-layout (lane: query=n16, keys=quad*4+r)
// is EXACTLY the A-layout of P for 16x16x16 MFMA (m=lane&15, k=quad*4+j).
// PV: o[dt] += mfma_16x16x16(p_kc, V[key kc*16+quad*4..+3][d=dt*16+n16]).
// 64 q-rows/block (16/wave) -> 1024 blocks, 4 blocks/CU. LDS 16KB (K,V only).
// ---------------------------------------------------------------------------
__global__ __launch_bounds__(256) void attn3(
    const f16* __restrict__ Q, const f16* __restrict__ K,
    const f16* __restrict__ Vt, f16* __restrict__ AO) {
  const int bh = blockIdx.y;
  const int b = bh >> 4, h = bh & 15;
  const int qb = blockIdx.x * 64;
  const int t = threadIdx.x;
  const int lane = t & 63, wid = t >> 6;
  const int quad = lane >> 4, n16 = lane & 15;

  const f16* __restrict__ Qp = Q + (size_t)bh * N_ * D_;
  const f16* __restrict__ Kp = K + (size_t)bh * N_ * D_;
  const f16* __restrict__ Vp = Vt + (size_t)bh * D_ * N_;  // [d][n]

  __shared__ f16 Ks[64 * 64];  // [key][d], XOR-8 granule swizzle
  __shared__ f16 Vs[64 * 64];  // [d][key], XOR-8 granule swizzle

  // Q B-fragments: one 16-query chunk per wave, two 32-wide k chunks
  const f16* qp = Qp + (size_t)(qb + wid * 16 + n16) * D_ + quad * 8;
  const f16x8 qf0 = *(const f16x8*)(qp);
  const f16x8 qf1 = *(const f16x8*)(qp + 32);

  f32x4 o[4];
#pragma unroll
  for (int i = 0; i < 4; ++i) o[i] = (f32x4){0.f, 0.f, 0.f, 0.f};
  float lsum = 0.f;

  // staging: issue j covers rows j*32 + wid*8 + lane/8, granule lane&7
  int srow0 = wid * 8 + (lane >> 3);
  int srow1 = 32 + srow0;
  int gl0 = ((lane & 7) ^ (srow0 & 7)) * 8;
  int gl1 = ((lane & 7) ^ (srow1 & 7)) * 8;
  const f16* gK0 = Kp + (size_t)srow0 * D_ + gl0;
  const f16* gK1 = Kp + (size_t)srow1 * D_ + gl1;
  const f16* gV0 = Vp + (size_t)srow0 * N_ + gl0;
  const f16* gV1 = Vp + (size_t)srow1 * N_ + gl1;
  f16* lK0 = &Ks[wid * 512];
  f16* lK1 = &Ks[2048 + wid * 512];
  f16* lV0 = &Vs[wid * 512];
  f16* lV1 = &Vs[2048 + wid * 512];

  // K fragment swizzled granule offsets (row = kc*16+n16, row&7 = n16&7)
  const int fs0 = (quad ^ (n16 & 7)) * 8;
  const int fs1 = ((quad + 4) ^ (n16 & 7)) * 8;
  // V b64 read: row d=dt*16+n16, logical granule kc*2+(quad>>1), 8B offset (quad&1)*4
  int voff[4];
#pragma unroll
  for (int kc = 0; kc < 4; ++kc)
    voff[kc] = n16 * 64 + (((kc * 2 + (quad >> 1)) ^ (n16 & 7)) * 8) + (quad & 1) * 4;

  for (int kt = 0; kt < N_; kt += 64) {
    __syncthreads();
    cp16(lK0, gK0); cp16(lK1, gK1);
    cp16(lV0, gV0); cp16(lV1, gV1);
    gK0 += 64 * D_; gK1 += 64 * D_; gV0 += 64; gV1 += 64;
    __syncthreads();

    // S^T = K @ Q^T : lane holds keys kc*16+quad*4+r for query n16
    f32x4 s[4];
#pragma unroll
    for (int kc = 0; kc < 4; ++kc) {
      const f16x8 kf0 = *(const f16x8*)(&Ks[(kc * 16 + n16) * 64 + fs0]);
      const f16x8 kf1 = *(const f16x8*)(&Ks[(kc * 16 + n16) * 64 + fs1]);
      f32x4 sv = (f32x4){0.f, 0.f, 0.f, 0.f};
      sv = MFMA16(kf0, qf0, sv);
      sv = MFMA16(kf1, qf1, sv);
      s[kc] = sv;
    }

    // p = 2^s (log2e folded into Q), in-register cvt to PV A-frags
    f16x4 pa[4];
#pragma unroll
    for (int kc = 0; kc < 4; ++kc)
#pragma unroll
      for (int r = 0; r < 4; ++r) {
        float p = __builtin_amdgcn_exp2f(s[kc][r]);
        lsum += p;
        pa[kc][r] = (f16)p;
      }

    // O += P @ V : 16x16x16 MFMA, V B-frags as b64 reads from V^T tile
#pragma unroll
    for (int kc = 0; kc < 4; ++kc)
#pragma unroll
      for (int dt = 0; dt < 4; ++dt) {
        const f16x4 vb = *(const f16x4*)(&Vs[dt * 1024 + voff[kc]]);
        o[dt] = MFMA16K(pa[kc], vb, o[dt]);
      }
  }

  // lsum currently partial over this quad's 16 keys; reduce across quads
  lsum += __shfl_xor(lsum, 16);
  lsum += __shfl_xor(lsum, 32);

  // normalize + write AO f16 [B,N,H]; O rows = query quad*4+r, cols d=dt*16+n16
#pragma unroll
  for (int r = 0; r < 4; ++r) {
    float inv = 1.0f / __shfl(lsum, quad * 4 + r);
    int nrow = qb + wid * 16 + quad * 4 + r;
    f16* aop = AO + ((size_t)(b * N_ + nrow)) * H_ + h * 64;
#pragma unroll
    for (int dt = 0; dt < 4; ++dt)
      aop[dt * 16 + n16] = (f16)(o[dt][r] * inv);
  }
}

// ---------------------------------------------------------------------------
// Output GEMM, m97-style: out[4096,1024] = AO_f16 @ WoutT^T + bout (f32 out)
// ---------------------------------------------------------------------------
__global__ __launch_bounds__(256) void out_mfma(
    const f16* __restrict__ A, const f16* __restrict__ Wt,
    const float* __restrict__ bias, float* __restrict__ out) {
  const int bid = blockIdx.x;
  const int rb = (bid & 31) * 128;
  const int cb = (bid >> 5) * 128;
  const int t = threadIdx.x;
  const int lane = t & 63, wid = t >> 6;
  const int quad = lane >> 4, n16 = lane & 15;
  const int wm = wid >> 1, wn = wid & 1;

  __shared__ f16 As[128 * 32];
  __shared__ f16 Bs[128 * 32];

  f32x4 acc[4][4];
#pragma unroll
  for (int i = 0; i < 4; ++i)
#pragma unroll
    for (int j = 0; j < 4; ++j) acc[i][j] = (f32x4){0.f, 0.f, 0.f, 0.f};

  int srow0 = wid * 16 + (lane >> 2);
  int srow1 = 64 + srow0;
  int gl0 = ((lane & 3) ^ ((srow0 >> 1) & 3)) * 8;
  int gl1 = ((lane & 3) ^ ((srow1 >> 1) & 3)) * 8;
  const f16* gA0 = A + (size_t)(rb + srow0) * H_ + gl0;
  const f16* gA1 = A + (size_t)(rb + srow1) * H_ + gl1;
  const f16* gB0 = Wt + (size_t)(cb + srow0) * H_ + gl0;
  const f16* gB1 = Wt + (size_t)(cb + srow1) * H_ + gl1;
  f16* lA0 = &As[wid * 512];
  f16* lA1 = &As[2048 + wid * 512];
  f16* lB0 = &Bs[wid * 512];
  f16* lB1 = &Bs[2048 + wid * 512];

  const int fsw = (quad ^ ((n16 >> 1) & 3)) * 8;
  int aoff[4], boff[4];
#pragma unroll
  for (int i = 0; i < 4; ++i) {
    aoff[i] = (wm * 64 + i * 16 + n16) * 32 + fsw;
    boff[i] = (wn * 64 + i * 16 + n16) * 32 + fsw;
  }

  for (int kt = 0; kt < H_; kt += 32) {
    __syncthreads();
    cp16(lA0, gA0); cp16(lA1, gA1);
    cp16(lB0, gB0); cp16(lB1, gB1);
    gA0 += 32; gA1 += 32; gB0 += 32; gB1 += 32;
    __syncthreads();

    f16x8 af[4], bf[4];
#pragma unroll
    for (int mt = 0; mt < 4; ++mt) af[mt] = *(const f16x8*)(&As[aoff[mt]]);
#pragma unroll
    for (int nt = 0; nt < 4; ++nt) bf[nt] = *(const f16x8*)(&Bs[boff[nt]]);
#pragma unroll
    for (int mt = 0; mt < 4; ++mt)
#pragma unroll
      for (int nt = 0; nt < 4; ++nt)
        acc[mt][nt] = MFMA16(af[mt], bf[nt], acc[mt][nt]);
  }

#pragma unroll
  for (int nt = 0; nt < 4; ++nt) {
    int gcol = cb + wn * 64 + nt * 16 + n16;
    float bv = bias[gcol];
#pragma unroll
    for (int mt = 0; mt < 4; ++mt)
#pragma unroll
      for (int r = 0; r < 4; ++r) {
        int grow = rb + wm * 64 + mt * 16 + quad * 4 + r;
        out[(size_t)grow * H_ + gcol] = acc[mt][nt][r] + bv;
      }
  }
}

extern "C" void kernel_launch(void* const* d_in, const int* in_sizes, int n_in,
                              void* d_out, int out_size, void* d_ws, size_t ws_size,
                              hipStream_t stream) {
  const float* x    = (const float*)d_in[0];
  const float* x2   = (const float*)d_in[1];
  const float* Wqkv = (const float*)d_in[2];
  const float* Wout = (const float*)d_in[3];
  const float* bout = (const float*)d_in[4];
  float* out = (float*)d_out;

  const size_t per = (size_t)B_ * NH_ * N_ * D_;   // 4M f16 elements
  f16* Xc    = (f16*)d_ws;
  f16* X2c   = Xc + per;
  f16* Qw    = X2c + per;
  f16* Kw    = Qw + per;
  f16* Vw    = Kw + per;
  f16* Vtw   = Vw + per;
  f16* AO    = Vtw + per;
  f16* WqkvT = AO + per;                      // [3072][1024]
  f16* WoutT = WqkvT + (size_t)3072 * 1024;   // [1024][1024]

  convf16<<<dim3(2048, 2), 256, 0, stream>>>(x, x2, Xc, X2c);
  transw<<<dim3(48, 16), 256, 0, stream>>>(Wqkv, WqkvT, H_, 3 * H_);
  transw<<<dim3(16, 16), 256, 0, stream>>>(Wout, WoutT, H_, H_);
  qkv_mfma<<<dim3(768), 256, 0, stream>>>(Xc, X2c, WqkvT, Qw, Kw, Vw);
  transv<<<dim3(32, 32), 256, 0, stream>>>(Vw, Vtw);
  attn3<<<dim3(32, 32), 256, 0, stream>>>(Qw, Kw, Vtw, AO);
  out_mfma<<<dim3(256), 256, 0, stream>>>(AO, WoutT, bout, out);
}